// Round 13
// baseline (3249.360 us; speedup 1.0000x reference)
//
#include <hip/hip_runtime.h>
#include <cstdint>
#include <cstddef>

typedef unsigned short u16;
typedef unsigned char u8;
typedef unsigned long long u64;
typedef __attribute__((ext_vector_type(8))) short s16x8;
typedef __attribute__((ext_vector_type(8))) _Float16 f16x8;
typedef __attribute__((ext_vector_type(4))) float f32x4;
typedef __attribute__((ext_vector_type(4))) unsigned int u32x4;
typedef __attribute__((ext_vector_type(4))) unsigned short u16x4;

#define AGENT __HIP_MEMORY_SCOPE_AGENT

namespace {
constexpr int NWG  = 256;
constexpr int NTHR = 256;
constexpr int Bb   = 256;
constexpr int Tt   = 256;
constexpr int EMB_ = 256;
constexpr int HID_ = 512;
constexpr int NCLS = 32000;

constexpr float S_HM = 1.0f / 255.0f;    // H1m u8 scale (sigmoid, unsigned)
constexpr float S_H1 = 1.0f / 127.5f;    // H / H1 u8 scale (biased: v = u*S - 1)

// ---- LDS layout (bytes) ----
constexpr int OFF_W1  = 0;        // cell1: x bf16, H f16
constexpr int OFF_W3  = 49152;    // cell2: x bf16, H f16
constexpr int OFF_W2  = 98304;    // mix: all f16 (both operand halves u8-decoded)
constexpr int OFF_DS  = 131072;   // cell2 gate scratch [64][33] f32 (wave-disjoint rows)
constexpr int OFF_DS1 = 139520;   // cell1 gate scratch
constexpr int OFF_DSM = 147968;   // mix per-wave transpose / init colsum scratch
constexpr int OFF_C   = 150144;   // cell1 C state (bq reuse in final)
constexpr int OFF_C1  = 152192;   // cell2 C state
constexpr int OFF_B1  = 154240;   // bg - colsum(Wh)   (u8-bias folded)
constexpr int OFF_B3  = 154368;   // bg1 (H1m unsigned -> no fold)
constexpr int OFF_B2  = 154496;   // bh - colsum(Wxh) - colsum(Whh)
constexpr int SMEM_BYTES = 154560;

// ---- workspace layout ----
constexpr size_t WS_FL   = 0;                          // 256 x 128B
constexpr size_t WS_DONE = 32768;
constexpr size_t WS_HQ0  = 33792;                      // H u8 ping [B][512]
constexpr size_t WS_HQ1  = WS_HQ0 + (size_t)Bb * HID_;
constexpr size_t WS_H18  = WS_HQ1 + (size_t)Bb * HID_; // H1 u8
constexpr size_t WS_HM8  = WS_H18 + (size_t)Bb * HID_; // H1m u8
constexpr size_t WS_XE   = WS_HM8 + (size_t)Bb * HID_; // Xe bf16
}  // namespace

struct Params {
  const int* X; const float* Hin; const float* Cin; const float* E;
  const float* Wx[4];  const float* Wh[4];  const float* bg[4];
  const float* Wx1[4]; const float* Wh1[4]; const float* bg1[4];
  const float* Wxh; const float* Whh; const float* bh;
  const float* Whq; const float* bq;
  float* out; char* ws;
};

__device__ __forceinline__ u16 f2bf(float f) {
  union { float f; unsigned u; } v; v.f = f;
  unsigned r = v.u + 0x7FFFu + ((v.u >> 16) & 1u);
  return (u16)(r >> 16);
}
__device__ __forceinline__ u16 f2h(float f) {
  _Float16 h = (_Float16)f;
  union { _Float16 h; u16 u; } v; v.h = h; return v.u;
}
__device__ __forceinline__ float sigm(float x) { return 1.f / (1.f + __expf(-x)); }
__device__ __forceinline__ float tanh_(float x) {
  x = fminf(fmaxf(x, -10.f), 10.f);
  float e = __expf(-2.f * x);
  return (1.f - e) / (1.f + e);
}
__device__ __forceinline__ f32x4 mfma16(s16x8 a, s16x8 b, f32x4 c) {
  return __builtin_amdgcn_mfma_f32_16x16x32_bf16(a, b, c, 0, 0, 0);
}
__device__ __forceinline__ f32x4 mfma16h(f16x8 a, f16x8 b, f32x4 c) {
  return __builtin_amdgcn_mfma_f32_16x16x32_f16(a, b, c, 0, 0, 0);
}

// permuted u8 k-layout: consumer lane(q) load j covers frags 2j,2j+1 contiguously.
// k = kb*32 + q*8 + e  ->  pos = (kb>>1)*64 + q*16 + (kb&1)*8 + e   (bijective)
__device__ __forceinline__ int permk(int k) {
  return ((k >> 6) << 6) | (((k >> 3) & 3) << 4) | (((k >> 5) & 1) << 3) | (k & 7);
}

// decode 8 u8 (2 dwords) -> 8 f16 (exact: ints <=255)
__device__ __forceinline__ f16x8 dec8(unsigned lo, unsigned hi) {
  union { unsigned w[4]; f16x8 v; } o;
  float a, b;
  asm("v_cvt_f32_ubyte0 %0, %1" : "=v"(a) : "v"(lo));
  asm("v_cvt_f32_ubyte1 %0, %1" : "=v"(b) : "v"(lo));
  asm("v_cvt_pkrtz_f16_f32 %0, %1, %2" : "=v"(o.w[0]) : "v"(a), "v"(b));
  asm("v_cvt_f32_ubyte2 %0, %1" : "=v"(a) : "v"(lo));
  asm("v_cvt_f32_ubyte3 %0, %1" : "=v"(b) : "v"(lo));
  asm("v_cvt_pkrtz_f16_f32 %0, %1, %2" : "=v"(o.w[1]) : "v"(a), "v"(b));
  asm("v_cvt_f32_ubyte0 %0, %1" : "=v"(a) : "v"(hi));
  asm("v_cvt_f32_ubyte1 %0, %1" : "=v"(b) : "v"(hi));
  asm("v_cvt_pkrtz_f16_f32 %0, %1, %2" : "=v"(o.w[2]) : "v"(a), "v"(b));
  asm("v_cvt_f32_ubyte2 %0, %1" : "=v"(a) : "v"(hi));
  asm("v_cvt_f32_ubyte3 %0, %1" : "=v"(b) : "v"(hi));
  asm("v_cvt_pkrtz_f16_f32 %0, %1, %2" : "=v"(o.w[3]) : "v"(a), "v"(b));
  return o.v;
}
__device__ __forceinline__ unsigned enc4(float a, float b, float c2, float d) {
  unsigned ua = (unsigned)a, ub = (unsigned)b, uc = (unsigned)c2, ud = (unsigned)d;
  return ua | (ub << 8) | (uc << 16) | (ud << 24);
}
__device__ __forceinline__ unsigned enc4s(const float* hv) {   // biased signed encode
  return enc4((hv[0] + 1.f) * 127.5f + 0.5f, (hv[1] + 1.f) * 127.5f + 0.5f,
              (hv[2] + 1.f) * 127.5f + 0.5f, (hv[3] + 1.f) * 127.5f + 0.5f);
}

// ---- LLC bypass primitives ----
__device__ __forceinline__ void st4_llc(u8* pb, unsigned v) {
  __hip_atomic_store((unsigned*)pb, v, __ATOMIC_RELAXED, AGENT);
}
#define LD16A(d, b, off)                                                      \
  asm volatile("global_load_dwordx4 %0, %1, off offset:" #off " sc0 sc1"      \
               : "=&v"(d) : "v"(b) : "memory")

// u8 panel: 8 x 16B loads per lane = full 512B row across 4 lanes
__device__ __forceinline__ void ld_u8x8(u32x4* d, const u8* b) {
  LD16A(d[0], b, 0);   LD16A(d[1], b, 64);  LD16A(d[2], b, 128);
  LD16A(d[3], b, 192); LD16A(d[4], b, 256); LD16A(d[5], b, 320);
  LD16A(d[6], b, 384); LD16A(d[7], b, 448);
}
__device__ __forceinline__ void waitld() {
  asm volatile("s_waitcnt vmcnt(0)" ::: "memory");
  __builtin_amdgcn_sched_barrier(0);
}
#define WAITLDN(n) do {                                                       \
  asm volatile("s_waitcnt vmcnt(" #n ")" ::: "memory");                       \
  __builtin_amdgcn_sched_barrier(0); } while (0)
// intra-wave LDS write->read fence (wave-local transpose; no barrier needed)
__device__ __forceinline__ void waitlds() {
  asm volatile("s_waitcnt lgkmcnt(0)" ::: "memory");
  __builtin_amdgcn_sched_barrier(0);
}

// ---- counter barrier (poison-zeroed in init; rounds 3/6 lesson) ----
// Arrives are SOFTWARE-PIPELINED: placed after the next block of independent
// work so the syncthreads' vmcnt(0) store-ack drain overlaps useful compute.
// Delaying an arrive never breaks correctness (monotonic counters, every
// arrive unconditional); the drain-before-add invariant is preserved.
__device__ __forceinline__ void arrive_cnt(int* fl, int c) {
  __syncthreads();
  if (threadIdx.x == 0)
    (void)__hip_atomic_fetch_add(&fl[(c & 7) * 32 + 16], 1, __ATOMIC_RELAXED, AGENT);
}
__device__ __forceinline__ void wait_cnt(int* fl, int ph) {
  const int tgt = ph * 8;
  if (threadIdx.x < 8) {
    for (;;) {
      int v = __hip_atomic_load(&fl[threadIdx.x * 32 + 16], __ATOMIC_RELAXED, AGENT);
      if (!__any(v < tgt)) break;
      __builtin_amdgcn_s_sleep(1);
    }
  }
  __syncthreads();
  __builtin_amdgcn_fence(__ATOMIC_ACQUIRE, "workgroup");
}
__device__ __forceinline__ void groupbar_heavy(int* fl, int slot, int ph) {
  __syncthreads();
  if (threadIdx.x == 0)
    __hip_atomic_store(&fl[slot * 32], ph, __ATOMIC_RELEASE, AGENT);
  if (threadIdx.x < 64) {
    for (;;) {
      int v = __hip_atomic_load(&fl[threadIdx.x * 32], __ATOMIC_RELAXED, AGENT);
      if (!__any(v < ph)) break;
      __builtin_amdgcn_s_sleep(1);
    }
  }
  __syncthreads();
  __builtin_amdgcn_fence(__ATOMIC_ACQUIRE, "agent");
}
__device__ __forceinline__ void donebar(int* dn, int bi) {
  __syncthreads();
  if (threadIdx.x == 0)
    __hip_atomic_store(&dn[bi], 1, __ATOMIC_RELEASE, AGENT);
  for (;;) {
    int v = __hip_atomic_load(&dn[threadIdx.x], __ATOMIC_RELAXED, AGENT);
    if (!__any(v < 1)) break;
    __builtin_amdgcn_s_sleep(1);
  }
  __syncthreads();
  __builtin_amdgcn_fence(__ATOMIC_ACQUIRE, "agent");
}

// Wave-local gate epilogue for cell2-style phases: wave w owns rows row0..+15.
__device__ __forceinline__ void cell2_epi(char* smem, int offB, int offC,
                                          f32x4 acc0, f32x4 acc1, u8* Hdst,
                                          int g, int c, int w, int lane) {
  const int r = lane & 15, q = lane >> 4;
  const int row0 = w * 16;
  float* Ds = (float*)(smem + OFF_DS);
#pragma unroll
  for (int i = 0; i < 4; i++) {
    Ds[(row0 + q * 4 + i) * 33 + r]      = acc0[i];
    Ds[(row0 + q * 4 + i) * 33 + 16 + r] = acc1[i];
  }
  waitlds();
  const float* bs = (const float*)(smem + offB);
  float* Cs = (float*)(smem + offC);
  if (lane < 32) {
    int row = row0 + (lane >> 1), j0 = (lane & 1) * 4;
    float hv[4];
#pragma unroll
    for (int i = 0; i < 4; i++) {
      int j = j0 + i;
      float vi = Ds[row * 33 + 0 + j]  + bs[0 + j];
      float vf = Ds[row * 33 + 8 + j]  + bs[8 + j];
      float vo = Ds[row * 33 + 16 + j] + bs[16 + j];
      float vc = Ds[row * 33 + 24 + j] + bs[24 + j];
      float I = sigm(vi), F = sigm(vf), O = sigm(vo), Ct = tanh_(vc);
      float Cn = F * Cs[row * 8 + j] + I * Ct;
      Cs[row * 8 + j] = Cn;
      hv[i] = O * tanh_(Cn);
    }
    st4_llc(Hdst + (size_t)(g * 64 + row) * 512 + permk(c * 8 + j0), enc4s(hv));
  }
}

// Prologue cell1(0): 4 waves, u8 H in/out, f16 H-part MFMA, wave-local epilogue.
__device__ __forceinline__ void cell_phase_q(char* smem, int offW, int offB, int offC,
                                             const u16* Xt, const u8* Hrec, u8* Hdst,
                                             int g, int c, int w, int lane) {
  const int r = lane & 15, q = lane >> 4;
  const int row0 = w * 16;
  const u16* xrow = Xt + (size_t)(g * 64 + row0 + r) * EMB_;
  const u8* hrow = Hrec + (size_t)(g * 64 + row0 + r) * 512 + q * 16;
  const u16* wb = (const u16*)(smem + offW) + lane * 8;
  f32x4 acc0 = {0.f, 0.f, 0.f, 0.f}, acc1 = {0.f, 0.f, 0.f, 0.f};
#pragma unroll
  for (int kb = 0; kb < 8; kb++) {
    s16x8 a  = *(const s16x8*)(xrow + kb * 32 + q * 8);
    acc0 = mfma16(a, *(const s16x8*)(wb + (size_t)(kb * 2 + 0) * 512), acc0);
    acc1 = mfma16(a, *(const s16x8*)(wb + (size_t)(kb * 2 + 1) * 512), acc1);
  }
  u32x4 rw[8];
  ld_u8x8(rw, hrow);
  waitld();
  f32x4 ah0 = {0.f, 0.f, 0.f, 0.f}, ah1 = {0.f, 0.f, 0.f, 0.f};
#pragma unroll
  for (int jj = 0; jj < 8; jj++) {
    f16x8 f0 = dec8(rw[jj].x, rw[jj].y);
    f16x8 f1 = dec8(rw[jj].z, rw[jj].w);
    ah0 = mfma16h(f0, *(const f16x8*)(wb + (size_t)((2 * jj + 8) * 2 + 0) * 512), ah0);
    ah1 = mfma16h(f0, *(const f16x8*)(wb + (size_t)((2 * jj + 8) * 2 + 1) * 512), ah1);
    ah0 = mfma16h(f1, *(const f16x8*)(wb + (size_t)((2 * jj + 9) * 2 + 0) * 512), ah0);
    ah1 = mfma16h(f1, *(const f16x8*)(wb + (size_t)((2 * jj + 9) * 2 + 1) * 512), ah1);
  }
#pragma unroll
  for (int i = 0; i < 4; i++) { acc0[i] += ah0[i] * S_H1; acc1[i] += ah1[i] * S_H1; }
  cell2_epi(smem, offB, offC, acc0, acc1, Hdst, g, c, w, lane);
}

// cell1 on waves 2-3: u8 H in/out, wave-local (no barrier). Runs PRE-wait in B.
__device__ __forceinline__ void cell1_w23_q(char* smem, const u16* Xt, const u8* Hrec,
                                            u8* Hdst, int g, int c, int lane, int tid) {
  const int wv = (tid >> 6) - 2;
  const int r = lane & 15, q = lane >> 4;
  const u16* wb1 = (const u16*)(smem + OFF_W1) + lane * 8;
  float* D1 = (float*)(smem + OFF_DS1);
#pragma unroll
  for (int blk = 0; blk < 2; blk++) {
    const int rb = wv * 32 + blk * 16;
    const u16* xrow = Xt + (size_t)(g * 64 + rb + r) * EMB_;
    const u8* hrow = Hrec + (size_t)(g * 64 + rb + r) * 512 + q * 16;
    s16x8 xa[8];
#pragma unroll
    for (int kb = 0; kb < 8; kb++) xa[kb] = *(const s16x8*)(xrow + kb * 32 + q * 8);
    u32x4 rw[8];
    ld_u8x8(rw, hrow);
    f32x4 a0 = {0.f, 0.f, 0.f, 0.f}, a1 = {0.f, 0.f, 0.f, 0.f};
#pragma unroll
    for (int kb = 0; kb < 8; kb++) {
      a0 = mfma16(xa[kb], *(const s16x8*)(wb1 + (size_t)(kb * 2 + 0) * 512), a0);
      a1 = mfma16(xa[kb], *(const s16x8*)(wb1 + (size_t)(kb * 2 + 1) * 512), a1);
    }
    waitld();
    f32x4 ah0 = {0.f, 0.f, 0.f, 0.f}, ah1 = {0.f, 0.f, 0.f, 0.f};
#pragma unroll
    for (int jj = 0; jj < 8; jj++) {
      f16x8 f0 = dec8(rw[jj].x, rw[jj].y);
      f16x8 f1 = dec8(rw[jj].z, rw[jj].w);
      ah0 = mfma16h(f0, *(const f16x8*)(wb1 + (size_t)((2 * jj + 8) * 2 + 0) * 512), ah0);
      ah1 = mfma16h(f0, *(const f16x8*)(wb1 + (size_t)((2 * jj + 8) * 2 + 1) * 512), ah1);
      ah0 = mfma16h(f1, *(const f16x8*)(wb1 + (size_t)((2 * jj + 9) * 2 + 0) * 512), ah0);
      ah1 = mfma16h(f1, *(const f16x8*)(wb1 + (size_t)((2 * jj + 9) * 2 + 1) * 512), ah1);
    }
#pragma unroll
    for (int i = 0; i < 4; i++) {
      D1[(rb + q * 4 + i) * 33 + r]      = a0[i] + ah0[i] * S_H1;
      D1[(rb + q * 4 + i) * 33 + 16 + r] = a1[i] + ah1[i] * S_H1;
    }
  }
  waitlds();
  const float* bs = (const float*)(smem + OFF_B1);
  float* Cs = (float*)(smem + OFF_C);
  int t2 = tid - 128;
  int row = t2 >> 1, j0 = (t2 & 1) * 4;
  float hv[4];
#pragma unroll
  for (int i = 0; i < 4; i++) {
    int j = j0 + i;
    float vi = D1[row * 33 + 0 + j]  + bs[0 + j];
    float vf = D1[row * 33 + 8 + j]  + bs[8 + j];
    float vo = D1[row * 33 + 16 + j] + bs[16 + j];
    float vc = D1[row * 33 + 24 + j] + bs[24 + j];
    float I = sigm(vi), F = sigm(vf), O = sigm(vo), Ct = tanh_(vc);
    float Cn = F * Cs[row * 8 + j] + I * Ct;
    Cs[row * 8 + j] = Cn;
    hv[i] = O * tanh_(Cn);
  }
  st4_llc(Hdst + (size_t)(g * 64 + row) * 512 + permk(c * 8 + j0), enc4s(hv));
}

// mix part 1 (slack, waves 0-1): u8 H panel, f16 MFMA. Returns u8-scaled acc.
__device__ __forceinline__ f32x4 mix_part1_q(char* smem, const u8* Hq, int g, int c,
                                             int w, int lane) {
  const int r = lane & 15, q = lane >> 4;
  int rbase = g * 64 + (c & 1) * 32 + w * 16 + r;
  const u8* h0 = Hq + (size_t)rbase * 512 + q * 16;
  const u16* wb = (const u16*)(smem + OFF_W2) + lane * 8;
  u32x4 rw[8];
  ld_u8x8(rw, h0);
  waitld();
  f32x4 acc = {0.f, 0.f, 0.f, 0.f};
#pragma unroll
  for (int jj = 0; jj < 8; jj++) {
    acc = mfma16h(dec8(rw[jj].x, rw[jj].y), *(const f16x8*)(wb + (size_t)(2 * jj) * 512), acc);
    acc = mfma16h(dec8(rw[jj].z, rw[jj].w), *(const f16x8*)(wb + (size_t)(2 * jj + 1) * 512), acc);
  }
  return acc;
}

// mix part 2 (CRITICAL): u8 H1 panel, f16 MFMA, chunked vmcnt.
__device__ __forceinline__ void mix_part2(char* smem, f32x4 macc, const u8* H18,
                                          u8* HM8, int g, int c, int w, int lane) {
  const int r = lane & 15, q = lane >> 4;
  int rbase = g * 64 + (c & 1) * 32 + w * 16 + r;
  const u8* h1 = H18 + (size_t)rbase * 512 + q * 16;
  const u16* wb = (const u16*)(smem + OFF_W2) + lane * 8;
  u32x4 rw[8];
  ld_u8x8(rw, h1);
  __builtin_amdgcn_sched_barrier(0);
  f32x4 acch = {0.f, 0.f, 0.f, 0.f};
  WAITLDN(6);
#pragma unroll
  for (int j = 0; j < 2; j++) {
    acch = mfma16h(dec8(rw[j].x, rw[j].y), *(const f16x8*)(wb + (size_t)(16 + 2 * j) * 512), acch);
    acch = mfma16h(dec8(rw[j].z, rw[j].w), *(const f16x8*)(wb + (size_t)(17 + 2 * j) * 512), acch);
  }
  WAITLDN(4);
#pragma unroll
  for (int j = 2; j < 4; j++) {
    acch = mfma16h(dec8(rw[j].x, rw[j].y), *(const f16x8*)(wb + (size_t)(16 + 2 * j) * 512), acch);
    acch = mfma16h(dec8(rw[j].z, rw[j].w), *(const f16x8*)(wb + (size_t)(17 + 2 * j) * 512), acch);
  }
  WAITLDN(2);
#pragma unroll
  for (int j = 4; j < 6; j++) {
    acch = mfma16h(dec8(rw[j].x, rw[j].y), *(const f16x8*)(wb + (size_t)(16 + 2 * j) * 512), acch);
    acch = mfma16h(dec8(rw[j].z, rw[j].w), *(const f16x8*)(wb + (size_t)(17 + 2 * j) * 512), acch);
  }
  WAITLDN(0);
#pragma unroll
  for (int j = 6; j < 8; j++) {
    acch = mfma16h(dec8(rw[j].x, rw[j].y), *(const f16x8*)(wb + (size_t)(16 + 2 * j) * 512), acch);
    acch = mfma16h(dec8(rw[j].z, rw[j].w), *(const f16x8*)(wb + (size_t)(17 + 2 * j) * 512), acch);
  }
  f32x4 acc;
#pragma unroll
  for (int i = 0; i < 4; i++) acc[i] = (macc[i] + acch[i]) * S_H1;
  float* Dm = (float*)(smem + OFF_DSM) + (size_t)w * 16 * 17;
#pragma unroll
  for (int i = 0; i < 4; i++) Dm[(q * 4 + i) * 17 + r] = acc[i];
  waitlds();
  const float* b2 = (const float*)(smem + OFF_B2);
  int row2 = lane >> 2, j0 = (lane & 3) * 4;
  float s0 = sigm(Dm[row2 * 17 + j0 + 0] + b2[j0 + 0]);
  float s1 = sigm(Dm[row2 * 17 + j0 + 1] + b2[j0 + 1]);
  float s2 = sigm(Dm[row2 * 17 + j0 + 2] + b2[j0 + 2]);
  float s3 = sigm(Dm[row2 * 17 + j0 + 3] + b2[j0 + 3]);
  unsigned pv = enc4(s0 * 255.f + 0.5f, s1 * 255.f + 0.5f,
                     s2 * 255.f + 0.5f, s3 * 255.f + 0.5f);
  int colg = (c >> 1) * 16 + j0;
  st4_llc(HM8 + (size_t)(g * 64 + (c & 1) * 32 + w * 16 + row2) * 512 + permk(colg), pv);
}

__global__ __launch_bounds__(NTHR, 1) void lstm_pers(Params p) {
  extern __shared__ char smem[];
  const int tid = threadIdx.x;
  const int bi = blockIdx.x;
  const int w = tid >> 6, lane = tid & 63;
  const int g = bi >> 6, c = bi & 63;
  const int r = lane & 15, q = lane >> 4;

  int* fl = (int*)(p.ws + WS_FL) + g * 64 * 32;
  int* dn = (int*)(p.ws + WS_DONE);
  u8* Hq0 = (u8*)(p.ws + WS_HQ0);
  u8* Hq1 = (u8*)(p.ws + WS_HQ1);
  u8* H18 = (u8*)(p.ws + WS_H18);
  u8* HM8 = (u8*)(p.ws + WS_HM8);
  u16* Xe = (u16*)(p.ws + WS_XE);

  // zero phase counters (ws is POISONED; RMW needs explicit zero — rounds 3/6)
  if (tid == 0 && c < 8)
    __hip_atomic_store(&fl[c * 32 + 16], 0, __ATOMIC_RELAXED, AGENT);

  // ---- one-time init ----
  {
    u16* w1 = (u16*)(smem + OFF_W1);
    u16* w3 = (u16*)(smem + OFF_W3);
    int gate = tid >> 6, kk8 = (tid >> 3) & 7, j = tid & 7;
    int cc = gate * 8 + j;
    int n = cc >> 4, rr = cc & 15;
    int hid = c * 8 + j;
    for (int kk = kk8; kk < 768; kk += 8) {
      int kb = kk >> 5, q2 = (kk >> 3) & 3, e = kk & 7;
      size_t dst = ((size_t)(kb * 2 + n) * 64 + q2 * 16 + rr) * 8 + e;
      float s1 = (kk < 256) ? p.Wx[gate][(size_t)kk * HID_ + hid]
                            : p.Wh[gate][(size_t)(kk - 256) * HID_ + hid];
      float s3 = (kk < 256) ? p.Wx1[gate][(size_t)kk * HID_ + hid]
                            : p.Wh1[gate][(size_t)(kk - 256) * HID_ + hid];
      w1[dst] = (kk < 256) ? f2bf(s1) : f2h(s1);   // H-part f16 (u8-decoded operand)
      w3[dst] = (kk < 256) ? f2bf(s3) : f2h(s3);
    }
    {  // mix weights: all f16 (both operand halves are u8-decoded)
      u16* w2 = (u16*)(smem + OFF_W2);
      int kk16 = tid >> 4, j2 = tid & 15;
      int hid2 = (c >> 1) * 16 + j2;
      for (int kk = kk16; kk < 1024; kk += 16) {
        int kb = kk >> 5, q2 = (kk >> 3) & 3, e = kk & 7;
        size_t dst = ((size_t)kb * 64 + q2 * 16 + j2) * 8 + e;
        float s = (kk < 512) ? p.Wxh[(size_t)kk * HID_ + hid2]
                             : p.Whh[(size_t)(kk - 512) * HID_ + hid2];
        w2[dst] = f2h(s);
      }
    }
    // B1 = bg - colsum(Wh)  (u8-bias fold for cell1's H input)
    {
      float* scr = (float*)(smem + OFF_DSM);
      int col32 = tid & 31, part = tid >> 5;
      int gt = col32 >> 3, jj = col32 & 7;
      int hid1 = c * 8 + jj;
      float s = 0.f;
      for (int k = part * 64; k < part * 64 + 64; k++)
        s += p.Wh[gt][(size_t)k * HID_ + hid1];
      scr[col32 * 8 + part] = s;
      __syncthreads();
      if (tid < 32) {
        float t2 = 0.f;
        for (int i2 = 0; i2 < 8; i2++) t2 += scr[tid * 8 + i2];
        ((float*)(smem + OFF_B1))[tid] = p.bg[tid >> 3][c * 8 + (tid & 7)] - t2;
      }
      __syncthreads();
    }
    // B2 = bh - colsum(Wxh) - colsum(Whh)
    {
      float* scr = (float*)(smem + OFF_DSM);
      int col = tid & 15, part = tid >> 4;
      int hid2 = (c >> 1) * 16 + col;
      float s = 0.f;
      for (int k = part * 32; k < part * 32 + 32; k++)
        s += p.Whh[(size_t)k * HID_ + hid2] + p.Wxh[(size_t)k * HID_ + hid2];
      scr[col * 16 + part] = s;
      __syncthreads();
      if (tid < 16) {
        float t2 = 0.f;
        for (int i2 = 0; i2 < 16; i2++) t2 += scr[tid * 16 + i2];
        ((float*)(smem + OFF_B2))[tid] = p.bh[(c >> 1) * 16 + tid] - t2;
      }
      __syncthreads();
    }
    if (tid < 32) {   // B3 plain (H1m unsigned u8 -> no fold)
      ((float*)(smem + OFF_B3))[tid] = p.bg1[tid >> 3][c * 8 + (tid & 7)];
    }
    float* Cs = (float*)(smem + OFF_C);
    float* C1s = (float*)(smem + OFF_C1);
    for (int it = 0; it < 2; it++) {
      int idx = tid + it * 256;
      int row = idx >> 3, j8 = idx & 7;
      float v = p.Cin[(size_t)(g * 64 + row) * HID_ + c * 8 + j8];
      Cs[row * 8 + j8] = v;
      C1s[row * 8 + j8] = v;
    }
  }
  // H(-1) and H1(-1) u8 init from Hin (biased encode, permuted; normal stores)
  for (int it = 0; it < 2; it++) {
    int idx = bi * 512 + tid + it * 256;
    float v = p.Hin[idx];
    float vc2 = fminf(fmaxf(v, -0.999f), 0.999f);
    u8 ev = (u8)((vc2 + 1.f) * 127.5f + 0.5f);
    int row = idx >> 9, k = idx & 511;
    Hq1[(size_t)row * 512 + permk(k)] = ev;
    H18[(size_t)row * 512 + permk(k)] = ev;
  }
  // Embedding gather
  for (int tt = 0; tt < 4; tt++) {
    int t0 = c * 4 + tt;
    for (int pp = 0; pp < 16; pp++) {
      int b = g * 64 + w * 16 + pp;
      int tok = p.X[(size_t)b * Tt + t0];
      const float4* er = (const float4*)(p.E + (size_t)tok * EMB_);
      float4 v = er[lane];
      u16x4 u; u.x = f2bf(v.x); u.y = f2bf(v.y); u.z = f2bf(v.z); u.w = f2bf(v.w);
      *(u16x4*)(Xe + ((size_t)t0 * Bb + b) * EMB_ + lane * 4) = u;
    }
  }
  groupbar_heavy(fl, c, 1);

  int cph = 0;
  const u16* wb3 = (const u16*)(smem + OFF_W3) + lane * 8;

  // ---- P0: cell1(0): Hq1 -> Hq0 ----
  cell_phase_q(smem, OFF_W1, OFF_B1, OFF_C, Xe, Hq1, Hq0, g, c, w, lane);
  arrive_cnt(fl, c); ++cph;

  // ---- P1: mix(0) [w 0-1] + cell1(1) [w 2-3]; x-prework(A_0) before arrive ----
  wait_cnt(fl, cph);
  if (w < 2) {
    f32x4 macc = mix_part1_q(smem, Hq0, g, c, w, lane);
    mix_part2(smem, macc, H18, HM8, g, c, w, lane);
  } else {
    cell1_w23_q(smem, Xe + (size_t)1 * Bb * EMB_, Hq0, Hq1, g, c, lane, tid);
  }
  f32x4 accA0, accA1;   // software-pipelined x-part accumulators for cell2(t)
  {
    const u16* xrow = Xe + (size_t)(g * 64 + w * 16 + r) * EMB_;   // t=0
    s16x8 xa[8];
#pragma unroll
    for (int kb = 0; kb < 8; kb++) xa[kb] = *(const s16x8*)(xrow + kb * 32 + q * 8);
    accA0 = (f32x4){0.f, 0.f, 0.f, 0.f};
    accA1 = (f32x4){0.f, 0.f, 0.f, 0.f};
#pragma unroll
    for (int kb = 0; kb < 8; kb++) {
      accA0 = mfma16(xa[kb], *(const s16x8*)(wb3 + (size_t)(kb * 2 + 0) * 512), accA0);
      accA1 = mfma16(xa[kb], *(const s16x8*)(wb3 + (size_t)(kb * 2 + 1) * 512), accA1);
    }
  }
  arrive_cnt(fl, c); ++cph;     // P1 arrive (drains mix/cell1 stores under x-prework)

  // ---- steady state: pipelined arrives ----
  for (int t = 0; t < Tt - 1; t++) {
    // ---------- Phase A_t: cell2(t) ----------
    {
      wait_cnt(fl, cph);                   // B_{t-1} done -> H1m(t) readable
      const u8* hrow8 = HM8 + (size_t)(g * 64 + w * 16 + r) * 512 + q * 16;
      u32x4 rw[8];
      ld_u8x8(rw, hrow8);
      __builtin_amdgcn_sched_barrier(0);
      f32x4 acc0 = accA0, acc1 = accA1;
      f32x4 ah0 = {0.f, 0.f, 0.f, 0.f}, ah1 = {0.f, 0.f, 0.f, 0.f};
      WAITLDN(6);
#pragma unroll
      for (int jj = 0; jj < 2; jj++) {
        f16x8 f0 = dec8(rw[jj].x, rw[jj].y);
        f16x8 f1 = dec8(rw[jj].z, rw[jj].w);
        ah0 = mfma16h(f0, *(const f16x8*)(wb3 + (size_t)((2 * jj + 8) * 2 + 0) * 512), ah0);
        ah1 = mfma16h(f0, *(const f16x8*)(wb3 + (size_t)((2 * jj + 8) * 2 + 1) * 512), ah1);
        ah0 = mfma16h(f1, *(const f16x8*)(wb3 + (size_t)((2 * jj + 9) * 2 + 0) * 512), ah0);
        ah1 = mfma16h(f1, *(const f16x8*)(wb3 + (size_t)((2 * jj + 9) * 2 + 1) * 512), ah1);
      }
      WAITLDN(4);
#pragma unroll
      for (int jj = 2; jj < 4; jj++) {
        f16x8 f0 = dec8(rw[jj].x, rw[jj].y);
        f16x8 f1 = dec8(rw[jj].z, rw[jj].w);
        ah0 = mfma16h(f0, *(const f16x8*)(wb3 + (size_t)((2 * jj + 8) * 2 + 0) * 512), ah0);
        ah1 = mfma16h(f0, *(const f16x8*)(wb3 + (size_t)((2 * jj + 8) * 2 + 1) * 512), ah1);
        ah0 = mfma16h(f1, *(const f16x8*)(wb3 + (size_t)((2 * jj + 9) * 2 + 0) * 512), ah0);
        ah1 = mfma16h(f1, *(const f16x8*)(wb3 + (size_t)((2 * jj + 9) * 2 + 1) * 512), ah1);
      }
      WAITLDN(2);
#pragma unroll
      for (int jj = 4; jj < 6; jj++) {
        f16x8 f0 = dec8(rw[jj].x, rw[jj].y);
        f16x8 f1 = dec8(rw[jj].z, rw[jj].w);
        ah0 = mfma16h(f0, *(const f16x8*)(wb3 + (size_t)((2 * jj + 8) * 2 + 0) * 512), ah0);
        ah1 = mfma16h(f0, *(const f16x8*)(wb3 + (size_t)((2 * jj + 8) * 2 + 1) * 512), ah1);
        ah0 = mfma16h(f1, *(const f16x8*)(wb3 + (size_t)((2 * jj + 9) * 2 + 0) * 512), ah0);
        ah1 = mfma16h(f1, *(const f16x8*)(wb3 + (size_t)((2 * jj + 9) * 2 + 1) * 512), ah1);
      }
      WAITLDN(0);
#pragma unroll
      for (int jj = 6; jj < 8; jj++) {
        f16x8 f0 = dec8(rw[jj].x, rw[jj].y);
        f16x8 f1 = dec8(rw[jj].z, rw[jj].w);
        ah0 = mfma16h(f0, *(const f16x8*)(wb3 + (size_t)((2 * jj + 8) * 2 + 0) * 512), ah0);
        ah1 = mfma16h(f0, *(const f16x8*)(wb3 + (size_t)((2 * jj + 8) * 2 + 1) * 512), ah1);
        ah0 = mfma16h(f1, *(const f16x8*)(wb3 + (size_t)((2 * jj + 9) * 2 + 0) * 512), ah0);
        ah1 = mfma16h(f1, *(const f16x8*)(wb3 + (size_t)((2 * jj + 9) * 2 + 1) * 512), ah1);
      }
#pragma unroll
      for (int i = 0; i < 4; i++) {
        acc0[i] += ah0[i] * S_HM;
        acc1[i] += ah1[i] * S_HM;
      }
      cell2_epi(smem, OFF_B3, OFF_C1, acc0, acc1, H18, g, c, w, lane);
      // NO arrive yet: epilogue-store ack drains under B's pre-wait work below.
    }
    // ---------- Phase B_t: prework -> arriveA -> waitB -> mix2 -> x-prework -> arriveB ----------
    {
      const u8* Hnew = (t & 1) ? Hq0 : Hq1;   // H(t+1)
      u8* Hdst1      = (t & 1) ? Hq1 : Hq0;   // H(t+2)
      f32x4 macc = {0.f, 0.f, 0.f, 0.f};
      if (w < 2) {
        macc = mix_part1_q(smem, Hnew, g, c, w, lane);
      } else if (t + 2 < Tt) {
        cell1_w23_q(smem, Xe + (size_t)(t + 2) * Bb * EMB_, Hnew, Hdst1, g, c, lane, tid);
      }
      arrive_cnt(fl, c); ++cph;              // arrive A_t (cell2+cell1 stores drained here)
      wait_cnt(fl, cph);                     // A_t done everywhere -> H1(t) readable
      if (w < 2) mix_part2(smem, macc, H18, HM8, g, c, w, lane);
      // x-prework for cell2(t+1): hides mix2's store ack under xa loads + MFMAs
      {
        const u16* xrow = Xe + (size_t)(t + 1) * Bb * EMB_ +
                          (size_t)(g * 64 + w * 16 + r) * EMB_;
        s16x8 xa[8];
#pragma unroll
        for (int kb = 0; kb < 8; kb++) xa[kb] = *(const s16x8*)(xrow + kb * 32 + q * 8);
        accA0 = (f32x4){0.f, 0.f, 0.f, 0.f};
        accA1 = (f32x4){0.f, 0.f, 0.f, 0.f};
#pragma unroll
        for (int kb = 0; kb < 8; kb++) {
          accA0 = mfma16(xa[kb], *(const s16x8*)(wb3 + (size_t)(kb * 2 + 0) * 512), accA0);
          accA1 = mfma16(xa[kb], *(const s16x8*)(wb3 + (size_t)(kb * 2 + 1) * 512), accA1);
        }
      }
      arrive_cnt(fl, c); ++cph;              // arrive B_t
    }
  }

  // ---- epilogue: cell2(255) (x-part already in accA0/1) ----
  {
    wait_cnt(fl, cph);
    const u8* hrow8 = HM8 + (size_t)(g * 64 + w * 16 + r) * 512 + q * 16;
    u32x4 rw[8];
    ld_u8x8(rw, hrow8);
    waitld();
    f32x4 acc0 = accA0, acc1 = accA1;
    f32x4 ah0 = {0.f, 0.f, 0.f, 0.f}, ah1 = {0.f, 0.f, 0.f, 0.f};
#pragma unroll
    for (int jj = 0; jj < 8; jj++) {
      f16x8 f0 = dec8(rw[jj].x, rw[jj].y);
      f16x8 f1 = dec8(rw[jj].z, rw[jj].w);
      ah0 = mfma16h(f0, *(const f16x8*)(wb3 + (size_t)((2 * jj + 8) * 2 + 0) * 512), ah0);
      ah1 = mfma16h(f0, *(const f16x8*)(wb3 + (size_t)((2 * jj + 8) * 2 + 1) * 512), ah1);
      ah0 = mfma16h(f1, *(const f16x8*)(wb3 + (size_t)((2 * jj + 9) * 2 + 0) * 512), ah0);
      ah1 = mfma16h(f1, *(const f16x8*)(wb3 + (size_t)((2 * jj + 9) * 2 + 1) * 512), ah1);
    }
#pragma unroll
    for (int i = 0; i < 4; i++) {
      acc0[i] += ah0[i] * S_HM;
      acc1[i] += ah1[i] * S_HM;
    }
    cell2_epi(smem, OFF_B3, OFF_C1, acc0, acc1, H18, g, c, w, lane);
  }

  // ---- final GEMM: u8 H1 (cached loads post-donebar), f16 Wf, bias-corrected ----
  donebar(dn, bi);
  if (bi < 250) {
    const int n0 = bi * 128;
    _Float16* Wf = (_Float16*)smem;   // [16 kb][8 nt][64 lane][8] f16
    for (int idx = tid; idx < 512 * 128; idx += NTHR) {
      int k = idx >> 7, nn2 = idx & 127;
      int nt = nn2 >> 4, rr = nn2 & 15;
      int kb = k >> 5, q2 = (k >> 3) & 3, e = k & 7;
      Wf[((size_t)(kb * 8 + nt) * 64 + q2 * 16 + rr) * 8 + e] =
          (_Float16)p.Whq[(size_t)k * NCLS + n0 + nn2];
    }
    float* bqs = (float*)(smem + OFF_C);
    __syncthreads();
    if (tid < 128) {       // bqs = bq - colsum(Whq)  (u8 bias-fold), from LDS
      int nt = tid >> 4, rr = tid & 15;
      float s = 0.f;
      for (int kb = 0; kb < 16; kb++)
        for (int q2 = 0; q2 < 4; q2++)
#pragma unroll
          for (int e = 0; e < 8; e++)
            s += (float)Wf[((size_t)(kb * 8 + nt) * 64 + q2 * 16 + rr) * 8 + e];
      bqs[tid] = p.bq[n0 + tid] - s;
    }
    __syncthreads();
    const int r2 = lane & 15, q2 = lane >> 4;
    for (int mt = 0; mt < 4; mt++) {
      int rowb = mt * 64 + w * 16;
      const u8* h1base = H18 + (size_t)(rowb + r2) * 512 + q2 * 16;
      f16x8 haf[16];
#pragma unroll
      for (int jj = 0; jj < 8; jj++) {
        u32x4 rwv = *(const u32x4*)(h1base + jj * 64);
        haf[2 * jj]     = dec8(rwv.x, rwv.y);
        haf[2 * jj + 1] = dec8(rwv.z, rwv.w);
      }
      f32x4 acc[8];
#pragma unroll
      for (int nt = 0; nt < 8; nt++) acc[nt] = (f32x4){0.f, 0.f, 0.f, 0.f};
      for (int kb = 0; kb < 16; kb++) {
#pragma unroll
        for (int nt = 0; nt < 8; nt++) {
          f16x8 b = *(const f16x8*)(Wf + ((size_t)(kb * 8 + nt) * 64 + lane) * 8);
          acc[nt] = mfma16h(haf[kb], b, acc[nt]);
        }
      }
#pragma unroll
      for (int nt = 0; nt < 8; nt++)
#pragma unroll
        for (int i = 0; i < 4; i++)
          p.out[(size_t)(rowb + q2 * 4 + i) * NCLS + n0 + nt * 16 + r2] =
              acc[nt][i] * S_H1 + bqs[nt * 16 + r2];
    }
  }
}

extern "C" void kernel_launch(void* const* d_in, const int* in_sizes, int n_in,
                              void* d_out, int out_size, void* d_ws, size_t ws_size,
                              hipStream_t stream) {
  (void)in_sizes; (void)n_in; (void)out_size; (void)ws_size;
  Params p;
  p.X   = (const int*)d_in[0];
  p.Hin = (const float*)d_in[1];
  p.Cin = (const float*)d_in[2];
  p.E   = (const float*)d_in[3];
  for (int gidx = 0; gidx < 4; gidx++) {
    int base = 4 + gidx * 6;
    p.Wx[gidx]  = (const float*)d_in[base + 0];
    p.Wh[gidx]  = (const float*)d_in[base + 1];
    p.bg[gidx]  = (const float*)d_in[base + 2];
    p.Wx1[gidx] = (const float*)d_in[base + 3];
    p.Wh1[gidx] = (const float*)d_in[base + 4];
    p.bg1[gidx] = (const float*)d_in[base + 5];
  }
  p.Wxh = (const float*)d_in[28];
  p.Whh = (const float*)d_in[29];
  p.bh  = (const float*)d_in[30];
  p.Whq = (const float*)d_in[31];
  p.bq  = (const float*)d_in[32];
  p.out = (float*)d_out;
  p.ws  = (char*)d_ws;

  hipFuncSetAttribute(reinterpret_cast<const void*>(lstm_pers),
                      hipFuncAttributeMaxDynamicSharedMemorySize, SMEM_BYTES);
  lstm_pers<<<dim3(NWG), dim3(NTHR), SMEM_BYTES, stream>>>(p);
}

// Round 14
// 3041.604 us; speedup vs baseline: 1.0683x; 1.0683x over previous
//
#include <hip/hip_runtime.h>
#include <cstdint>
#include <cstddef>

typedef unsigned short u16;
typedef unsigned char u8;
typedef unsigned long long u64;
typedef __attribute__((ext_vector_type(8))) short s16x8;
typedef __attribute__((ext_vector_type(8))) _Float16 f16x8;
typedef __attribute__((ext_vector_type(4))) float f32x4;
typedef __attribute__((ext_vector_type(4))) unsigned int u32x4;
typedef __attribute__((ext_vector_type(4))) unsigned short u16x4;

#define AGENT __HIP_MEMORY_SCOPE_AGENT

namespace {
constexpr int NWG  = 256;
constexpr int NTHR = 256;
constexpr int Bb   = 256;
constexpr int Tt   = 256;
constexpr int EMB_ = 256;
constexpr int HID_ = 512;
constexpr int NCLS = 32000;

constexpr float S_HM = 1.0f / 255.0f;    // H1m u8 scale (sigmoid, unsigned)
constexpr float S_H1 = 1.0f / 127.5f;    // H / H1 u8 scale (biased: v = u*S - 1)

// ---- LDS layout (bytes) ----
constexpr int OFF_W1  = 0;        // cell1: x bf16, H f16
constexpr int OFF_W3  = 49152;    // cell2: x bf16, H f16
constexpr int OFF_W2  = 98304;    // mix: all f16 (both operand halves u8-decoded)
constexpr int OFF_DS  = 131072;   // cell2 gate scratch [64][33] f32 (wave-disjoint rows)
constexpr int OFF_DS1 = 139520;   // cell1 gate scratch
constexpr int OFF_DSM = 147968;   // mix per-wave transpose / init colsum scratch
constexpr int OFF_C   = 150144;   // cell1 C state (bq reuse in final)
constexpr int OFF_C1  = 152192;   // cell2 C state
constexpr int OFF_B1  = 154240;   // bg - colsum(Wh)   (u8-bias folded)
constexpr int OFF_B3  = 154368;   // bg1 (H1m unsigned -> no fold)
constexpr int OFF_B2  = 154496;   // bh - colsum(Wxh) - colsum(Whh)
constexpr int SMEM_BYTES = 154560;

// ---- workspace layout ----
constexpr size_t WS_FL   = 0;                          // 256 x 128B
constexpr size_t WS_DONE = 32768;
constexpr size_t WS_HQ0  = 33792;                      // H u8 ping [B][512]
constexpr size_t WS_HQ1  = WS_HQ0 + (size_t)Bb * HID_;
constexpr size_t WS_H18  = WS_HQ1 + (size_t)Bb * HID_; // H1 u8
constexpr size_t WS_HM8  = WS_H18 + (size_t)Bb * HID_; // H1m u8
constexpr size_t WS_XE   = WS_HM8 + (size_t)Bb * HID_; // Xe bf16
}  // namespace

struct Params {
  const int* X; const float* Hin; const float* Cin; const float* E;
  const float* Wx[4];  const float* Wh[4];  const float* bg[4];
  const float* Wx1[4]; const float* Wh1[4]; const float* bg1[4];
  const float* Wxh; const float* Whh; const float* bh;
  const float* Whq; const float* bq;
  float* out; char* ws;
};

__device__ __forceinline__ u16 f2bf(float f) {
  union { float f; unsigned u; } v; v.f = f;
  unsigned r = v.u + 0x7FFFu + ((v.u >> 16) & 1u);
  return (u16)(r >> 16);
}
__device__ __forceinline__ u16 f2h(float f) {
  _Float16 h = (_Float16)f;
  union { _Float16 h; u16 u; } v; v.h = h; return v.u;
}
__device__ __forceinline__ float sigm(float x) { return 1.f / (1.f + __expf(-x)); }
__device__ __forceinline__ float tanh_(float x) {
  x = fminf(fmaxf(x, -10.f), 10.f);
  float e = __expf(-2.f * x);
  return (1.f - e) / (1.f + e);
}
__device__ __forceinline__ f32x4 mfma16(s16x8 a, s16x8 b, f32x4 c) {
  return __builtin_amdgcn_mfma_f32_16x16x32_bf16(a, b, c, 0, 0, 0);
}
__device__ __forceinline__ f32x4 mfma16h(f16x8 a, f16x8 b, f32x4 c) {
  return __builtin_amdgcn_mfma_f32_16x16x32_f16(a, b, c, 0, 0, 0);
}

// permuted u8 k-layout: consumer lane(q) load j covers frags 2j,2j+1 contiguously.
// k = kb*32 + q*8 + e  ->  pos = (kb>>1)*64 + q*16 + (kb&1)*8 + e   (bijective)
__device__ __forceinline__ int permk(int k) {
  return ((k >> 6) << 6) | (((k >> 3) & 3) << 4) | (((k >> 5) & 1) << 3) | (k & 7);
}

// decode 8 u8 (2 dwords) -> 8 f16 (exact: ints <=255)
__device__ __forceinline__ f16x8 dec8(unsigned lo, unsigned hi) {
  union { unsigned w[4]; f16x8 v; } o;
  float a, b;
  asm("v_cvt_f32_ubyte0 %0, %1" : "=v"(a) : "v"(lo));
  asm("v_cvt_f32_ubyte1 %0, %1" : "=v"(b) : "v"(lo));
  asm("v_cvt_pkrtz_f16_f32 %0, %1, %2" : "=v"(o.w[0]) : "v"(a), "v"(b));
  asm("v_cvt_f32_ubyte2 %0, %1" : "=v"(a) : "v"(lo));
  asm("v_cvt_f32_ubyte3 %0, %1" : "=v"(b) : "v"(lo));
  asm("v_cvt_pkrtz_f16_f32 %0, %1, %2" : "=v"(o.w[1]) : "v"(a), "v"(b));
  asm("v_cvt_f32_ubyte0 %0, %1" : "=v"(a) : "v"(hi));
  asm("v_cvt_f32_ubyte1 %0, %1" : "=v"(b) : "v"(hi));
  asm("v_cvt_pkrtz_f16_f32 %0, %1, %2" : "=v"(o.w[2]) : "v"(a), "v"(b));
  asm("v_cvt_f32_ubyte2 %0, %1" : "=v"(a) : "v"(hi));
  asm("v_cvt_f32_ubyte3 %0, %1" : "=v"(b) : "v"(hi));
  asm("v_cvt_pkrtz_f16_f32 %0, %1, %2" : "=v"(o.w[3]) : "v"(a), "v"(b));
  return o.v;
}
__device__ __forceinline__ unsigned enc4(float a, float b, float c2, float d) {
  unsigned ua = (unsigned)a, ub = (unsigned)b, uc = (unsigned)c2, ud = (unsigned)d;
  return ua | (ub << 8) | (uc << 16) | (ud << 24);
}
__device__ __forceinline__ unsigned enc4s(const float* hv) {   // biased signed encode
  return enc4((hv[0] + 1.f) * 127.5f + 0.5f, (hv[1] + 1.f) * 127.5f + 0.5f,
              (hv[2] + 1.f) * 127.5f + 0.5f, (hv[3] + 1.f) * 127.5f + 0.5f);
}

// ---- LLC bypass primitives ----
__device__ __forceinline__ void st4_llc(u8* pb, unsigned v) {
  __hip_atomic_store((unsigned*)pb, v, __ATOMIC_RELAXED, AGENT);
}
#define LD16A(d, b, off)                                                      \
  asm volatile("global_load_dwordx4 %0, %1, off offset:" #off " sc0 sc1"      \
               : "=&v"(d) : "v"(b) : "memory")

// u8 panel: 8 x 16B loads per lane = full 512B row across 4 lanes
__device__ __forceinline__ void ld_u8x8(u32x4* d, const u8* b) {
  LD16A(d[0], b, 0);   LD16A(d[1], b, 64);  LD16A(d[2], b, 128);
  LD16A(d[3], b, 192); LD16A(d[4], b, 256); LD16A(d[5], b, 320);
  LD16A(d[6], b, 384); LD16A(d[7], b, 448);
}
__device__ __forceinline__ void waitld() {
  asm volatile("s_waitcnt vmcnt(0)" ::: "memory");
  __builtin_amdgcn_sched_barrier(0);
}
#define WAITLDN(n) do {                                                       \
  asm volatile("s_waitcnt vmcnt(" #n ")" ::: "memory");                       \
  __builtin_amdgcn_sched_barrier(0); } while (0)
// intra-wave LDS write->read fence (wave-local transpose; no barrier needed)
__device__ __forceinline__ void waitlds() {
  asm volatile("s_waitcnt lgkmcnt(0)" ::: "memory");
  __builtin_amdgcn_sched_barrier(0);
}

// ---- counter barrier (poison-zeroed in init; rounds 3/6 lesson) ----
// Arrive-early / wait-late: the arrive's exposed store-ack drain is the price
// of an early signal; round 13 proved deferring it past slack work puts that
// work on the group critical cycle (last-arriver paces every waiter).
__device__ __forceinline__ void arrive_cnt(int* fl, int c) {
  __syncthreads();
  if (threadIdx.x == 0)
    (void)__hip_atomic_fetch_add(&fl[(c & 7) * 32 + 16], 1, __ATOMIC_RELAXED, AGENT);
}
__device__ __forceinline__ void wait_cnt(int* fl, int ph) {
  const int tgt = ph * 8;
  if (threadIdx.x < 8) {
    for (;;) {
      int v = __hip_atomic_load(&fl[threadIdx.x * 32 + 16], __ATOMIC_RELAXED, AGENT);
      if (!__any(v < tgt)) break;
      __builtin_amdgcn_s_sleep(1);
    }
  }
  __syncthreads();
  __builtin_amdgcn_fence(__ATOMIC_ACQUIRE, "workgroup");
}
__device__ __forceinline__ void groupbar_heavy(int* fl, int slot, int ph) {
  __syncthreads();
  if (threadIdx.x == 0)
    __hip_atomic_store(&fl[slot * 32], ph, __ATOMIC_RELEASE, AGENT);
  if (threadIdx.x < 64) {
    for (;;) {
      int v = __hip_atomic_load(&fl[threadIdx.x * 32], __ATOMIC_RELAXED, AGENT);
      if (!__any(v < ph)) break;
      __builtin_amdgcn_s_sleep(1);
    }
  }
  __syncthreads();
  __builtin_amdgcn_fence(__ATOMIC_ACQUIRE, "agent");
}
__device__ __forceinline__ void donebar(int* dn, int bi) {
  __syncthreads();
  if (threadIdx.x == 0)
    __hip_atomic_store(&dn[bi], 1, __ATOMIC_RELEASE, AGENT);
  for (;;) {
    int v = __hip_atomic_load(&dn[threadIdx.x], __ATOMIC_RELAXED, AGENT);
    if (!__any(v < 1)) break;
    __builtin_amdgcn_s_sleep(1);
  }
  __syncthreads();
  __builtin_amdgcn_fence(__ATOMIC_ACQUIRE, "agent");
}

// Wave-local gate epilogue for cell2-style phases: wave w owns rows row0..+15.
__device__ __forceinline__ void cell2_epi(char* smem, int offB, int offC,
                                          f32x4 acc0, f32x4 acc1, u8* Hdst,
                                          int g, int c, int w, int lane) {
  const int r = lane & 15, q = lane >> 4;
  const int row0 = w * 16;
  float* Ds = (float*)(smem + OFF_DS);
#pragma unroll
  for (int i = 0; i < 4; i++) {
    Ds[(row0 + q * 4 + i) * 33 + r]      = acc0[i];
    Ds[(row0 + q * 4 + i) * 33 + 16 + r] = acc1[i];
  }
  waitlds();
  const float* bs = (const float*)(smem + offB);
  float* Cs = (float*)(smem + offC);
  if (lane < 32) {
    int row = row0 + (lane >> 1), j0 = (lane & 1) * 4;
    float hv[4];
#pragma unroll
    for (int i = 0; i < 4; i++) {
      int j = j0 + i;
      float vi = Ds[row * 33 + 0 + j]  + bs[0 + j];
      float vf = Ds[row * 33 + 8 + j]  + bs[8 + j];
      float vo = Ds[row * 33 + 16 + j] + bs[16 + j];
      float vc = Ds[row * 33 + 24 + j] + bs[24 + j];
      float I = sigm(vi), F = sigm(vf), O = sigm(vo), Ct = tanh_(vc);
      float Cn = F * Cs[row * 8 + j] + I * Ct;
      Cs[row * 8 + j] = Cn;
      hv[i] = O * tanh_(Cn);
    }
    st4_llc(Hdst + (size_t)(g * 64 + row) * 512 + permk(c * 8 + j0), enc4s(hv));
  }
}

// Prologue cell1(0): 4 waves, u8 H in/out, f16 H-part MFMA, wave-local epilogue.
__device__ __forceinline__ void cell_phase_q(char* smem, int offW, int offB, int offC,
                                             const u16* Xt, const u8* Hrec, u8* Hdst,
                                             int g, int c, int w, int lane) {
  const int r = lane & 15, q = lane >> 4;
  const int row0 = w * 16;
  const u16* xrow = Xt + (size_t)(g * 64 + row0 + r) * EMB_;
  const u8* hrow = Hrec + (size_t)(g * 64 + row0 + r) * 512 + q * 16;
  const u16* wb = (const u16*)(smem + offW) + lane * 8;
  f32x4 acc0 = {0.f, 0.f, 0.f, 0.f}, acc1 = {0.f, 0.f, 0.f, 0.f};
#pragma unroll
  for (int kb = 0; kb < 8; kb++) {
    s16x8 a  = *(const s16x8*)(xrow + kb * 32 + q * 8);
    acc0 = mfma16(a, *(const s16x8*)(wb + (size_t)(kb * 2 + 0) * 512), acc0);
    acc1 = mfma16(a, *(const s16x8*)(wb + (size_t)(kb * 2 + 1) * 512), acc1);
  }
  u32x4 rw[8];
  ld_u8x8(rw, hrow);
  waitld();
  f32x4 ah0 = {0.f, 0.f, 0.f, 0.f}, ah1 = {0.f, 0.f, 0.f, 0.f};
#pragma unroll
  for (int jj = 0; jj < 8; jj++) {
    f16x8 f0 = dec8(rw[jj].x, rw[jj].y);
    f16x8 f1 = dec8(rw[jj].z, rw[jj].w);
    ah0 = mfma16h(f0, *(const f16x8*)(wb + (size_t)((2 * jj + 8) * 2 + 0) * 512), ah0);
    ah1 = mfma16h(f0, *(const f16x8*)(wb + (size_t)((2 * jj + 8) * 2 + 1) * 512), ah1);
    ah0 = mfma16h(f1, *(const f16x8*)(wb + (size_t)((2 * jj + 9) * 2 + 0) * 512), ah0);
    ah1 = mfma16h(f1, *(const f16x8*)(wb + (size_t)((2 * jj + 9) * 2 + 1) * 512), ah1);
  }
#pragma unroll
  for (int i = 0; i < 4; i++) { acc0[i] += ah0[i] * S_H1; acc1[i] += ah1[i] * S_H1; }
  cell2_epi(smem, offB, offC, acc0, acc1, Hdst, g, c, w, lane);
}

// cell1 on waves 2-3: u8 H in/out, wave-local (no barrier). Runs PRE-wait in B.
__device__ __forceinline__ void cell1_w23_q(char* smem, const u16* Xt, const u8* Hrec,
                                            u8* Hdst, int g, int c, int lane, int tid) {
  const int wv = (tid >> 6) - 2;
  const int r = lane & 15, q = lane >> 4;
  const u16* wb1 = (const u16*)(smem + OFF_W1) + lane * 8;
  float* D1 = (float*)(smem + OFF_DS1);
#pragma unroll
  for (int blk = 0; blk < 2; blk++) {
    const int rb = wv * 32 + blk * 16;
    const u16* xrow = Xt + (size_t)(g * 64 + rb + r) * EMB_;
    const u8* hrow = Hrec + (size_t)(g * 64 + rb + r) * 512 + q * 16;
    s16x8 xa[8];
#pragma unroll
    for (int kb = 0; kb < 8; kb++) xa[kb] = *(const s16x8*)(xrow + kb * 32 + q * 8);
    u32x4 rw[8];
    ld_u8x8(rw, hrow);
    f32x4 a0 = {0.f, 0.f, 0.f, 0.f}, a1 = {0.f, 0.f, 0.f, 0.f};
#pragma unroll
    for (int kb = 0; kb < 8; kb++) {
      a0 = mfma16(xa[kb], *(const s16x8*)(wb1 + (size_t)(kb * 2 + 0) * 512), a0);
      a1 = mfma16(xa[kb], *(const s16x8*)(wb1 + (size_t)(kb * 2 + 1) * 512), a1);
    }
    waitld();
    f32x4 ah0 = {0.f, 0.f, 0.f, 0.f}, ah1 = {0.f, 0.f, 0.f, 0.f};
#pragma unroll
    for (int jj = 0; jj < 8; jj++) {
      f16x8 f0 = dec8(rw[jj].x, rw[jj].y);
      f16x8 f1 = dec8(rw[jj].z, rw[jj].w);
      ah0 = mfma16h(f0, *(const f16x8*)(wb1 + (size_t)((2 * jj + 8) * 2 + 0) * 512), ah0);
      ah1 = mfma16h(f0, *(const f16x8*)(wb1 + (size_t)((2 * jj + 8) * 2 + 1) * 512), ah1);
      ah0 = mfma16h(f1, *(const f16x8*)(wb1 + (size_t)((2 * jj + 9) * 2 + 0) * 512), ah0);
      ah1 = mfma16h(f1, *(const f16x8*)(wb1 + (size_t)((2 * jj + 9) * 2 + 1) * 512), ah1);
    }
#pragma unroll
    for (int i = 0; i < 4; i++) {
      D1[(rb + q * 4 + i) * 33 + r]      = a0[i] + ah0[i] * S_H1;
      D1[(rb + q * 4 + i) * 33 + 16 + r] = a1[i] + ah1[i] * S_H1;
    }
  }
  waitlds();
  const float* bs = (const float*)(smem + OFF_B1);
  float* Cs = (float*)(smem + OFF_C);
  int t2 = tid - 128;
  int row = t2 >> 1, j0 = (t2 & 1) * 4;
  float hv[4];
#pragma unroll
  for (int i = 0; i < 4; i++) {
    int j = j0 + i;
    float vi = D1[row * 33 + 0 + j]  + bs[0 + j];
    float vf = D1[row * 33 + 8 + j]  + bs[8 + j];
    float vo = D1[row * 33 + 16 + j] + bs[16 + j];
    float vc = D1[row * 33 + 24 + j] + bs[24 + j];
    float I = sigm(vi), F = sigm(vf), O = sigm(vo), Ct = tanh_(vc);
    float Cn = F * Cs[row * 8 + j] + I * Ct;
    Cs[row * 8 + j] = Cn;
    hv[i] = O * tanh_(Cn);
  }
  st4_llc(Hdst + (size_t)(g * 64 + row) * 512 + permk(c * 8 + j0), enc4s(hv));
}

// mix part 1 (slack, waves 0-1): u8 H panel, f16 MFMA. Returns u8-scaled acc.
__device__ __forceinline__ f32x4 mix_part1_q(char* smem, const u8* Hq, int g, int c,
                                             int w, int lane) {
  const int r = lane & 15, q = lane >> 4;
  int rbase = g * 64 + (c & 1) * 32 + w * 16 + r;
  const u8* h0 = Hq + (size_t)rbase * 512 + q * 16;
  const u16* wb = (const u16*)(smem + OFF_W2) + lane * 8;
  u32x4 rw[8];
  ld_u8x8(rw, h0);
  waitld();
  f32x4 acc = {0.f, 0.f, 0.f, 0.f};
#pragma unroll
  for (int jj = 0; jj < 8; jj++) {
    acc = mfma16h(dec8(rw[jj].x, rw[jj].y), *(const f16x8*)(wb + (size_t)(2 * jj) * 512), acc);
    acc = mfma16h(dec8(rw[jj].z, rw[jj].w), *(const f16x8*)(wb + (size_t)(2 * jj + 1) * 512), acc);
  }
  return acc;
}

// mix part 2 (CRITICAL): u8 H1 panel, f16 MFMA, chunked vmcnt.
__device__ __forceinline__ void mix_part2(char* smem, f32x4 macc, const u8* H18,
                                          u8* HM8, int g, int c, int w, int lane) {
  const int r = lane & 15, q = lane >> 4;
  int rbase = g * 64 + (c & 1) * 32 + w * 16 + r;
  const u8* h1 = H18 + (size_t)rbase * 512 + q * 16;
  const u16* wb = (const u16*)(smem + OFF_W2) + lane * 8;
  u32x4 rw[8];
  ld_u8x8(rw, h1);
  __builtin_amdgcn_sched_barrier(0);
  f32x4 acch = {0.f, 0.f, 0.f, 0.f};
  WAITLDN(6);
#pragma unroll
  for (int j = 0; j < 2; j++) {
    acch = mfma16h(dec8(rw[j].x, rw[j].y), *(const f16x8*)(wb + (size_t)(16 + 2 * j) * 512), acch);
    acch = mfma16h(dec8(rw[j].z, rw[j].w), *(const f16x8*)(wb + (size_t)(17 + 2 * j) * 512), acch);
  }
  WAITLDN(4);
#pragma unroll
  for (int j = 2; j < 4; j++) {
    acch = mfma16h(dec8(rw[j].x, rw[j].y), *(const f16x8*)(wb + (size_t)(16 + 2 * j) * 512), acch);
    acch = mfma16h(dec8(rw[j].z, rw[j].w), *(const f16x8*)(wb + (size_t)(17 + 2 * j) * 512), acch);
  }
  WAITLDN(2);
#pragma unroll
  for (int j = 4; j < 6; j++) {
    acch = mfma16h(dec8(rw[j].x, rw[j].y), *(const f16x8*)(wb + (size_t)(16 + 2 * j) * 512), acch);
    acch = mfma16h(dec8(rw[j].z, rw[j].w), *(const f16x8*)(wb + (size_t)(17 + 2 * j) * 512), acch);
  }
  WAITLDN(0);
#pragma unroll
  for (int j = 6; j < 8; j++) {
    acch = mfma16h(dec8(rw[j].x, rw[j].y), *(const f16x8*)(wb + (size_t)(16 + 2 * j) * 512), acch);
    acch = mfma16h(dec8(rw[j].z, rw[j].w), *(const f16x8*)(wb + (size_t)(17 + 2 * j) * 512), acch);
  }
  f32x4 acc;
#pragma unroll
  for (int i = 0; i < 4; i++) acc[i] = (macc[i] + acch[i]) * S_H1;
  float* Dm = (float*)(smem + OFF_DSM) + (size_t)w * 16 * 17;
#pragma unroll
  for (int i = 0; i < 4; i++) Dm[(q * 4 + i) * 17 + r] = acc[i];
  waitlds();
  const float* b2 = (const float*)(smem + OFF_B2);
  int row2 = lane >> 2, j0 = (lane & 3) * 4;
  float s0 = sigm(Dm[row2 * 17 + j0 + 0] + b2[j0 + 0]);
  float s1 = sigm(Dm[row2 * 17 + j0 + 1] + b2[j0 + 1]);
  float s2 = sigm(Dm[row2 * 17 + j0 + 2] + b2[j0 + 2]);
  float s3 = sigm(Dm[row2 * 17 + j0 + 3] + b2[j0 + 3]);
  unsigned pv = enc4(s0 * 255.f + 0.5f, s1 * 255.f + 0.5f,
                     s2 * 255.f + 0.5f, s3 * 255.f + 0.5f);
  int colg = (c >> 1) * 16 + j0;
  st4_llc(HM8 + (size_t)(g * 64 + (c & 1) * 32 + w * 16 + row2) * 512 + permk(colg), pv);
}

__global__ __launch_bounds__(NTHR, 1) void lstm_pers(Params p) {
  extern __shared__ char smem[];
  const int tid = threadIdx.x;
  const int bi = blockIdx.x;
  const int w = tid >> 6, lane = tid & 63;
  const int g = bi >> 6, c = bi & 63;
  const int r = lane & 15, q = lane >> 4;

  int* fl = (int*)(p.ws + WS_FL) + g * 64 * 32;
  int* dn = (int*)(p.ws + WS_DONE);
  u8* Hq0 = (u8*)(p.ws + WS_HQ0);
  u8* Hq1 = (u8*)(p.ws + WS_HQ1);
  u8* H18 = (u8*)(p.ws + WS_H18);
  u8* HM8 = (u8*)(p.ws + WS_HM8);
  u16* Xe = (u16*)(p.ws + WS_XE);

  // zero phase counters (ws is POISONED; RMW needs explicit zero — rounds 3/6)
  if (tid == 0 && c < 8)
    __hip_atomic_store(&fl[c * 32 + 16], 0, __ATOMIC_RELAXED, AGENT);

  // ---- one-time init ----
  {
    u16* w1 = (u16*)(smem + OFF_W1);
    u16* w3 = (u16*)(smem + OFF_W3);
    int gate = tid >> 6, kk8 = (tid >> 3) & 7, j = tid & 7;
    int cc = gate * 8 + j;
    int n = cc >> 4, rr = cc & 15;
    int hid = c * 8 + j;
    for (int kk = kk8; kk < 768; kk += 8) {
      int kb = kk >> 5, q2 = (kk >> 3) & 3, e = kk & 7;
      size_t dst = ((size_t)(kb * 2 + n) * 64 + q2 * 16 + rr) * 8 + e;
      float s1 = (kk < 256) ? p.Wx[gate][(size_t)kk * HID_ + hid]
                            : p.Wh[gate][(size_t)(kk - 256) * HID_ + hid];
      float s3 = (kk < 256) ? p.Wx1[gate][(size_t)kk * HID_ + hid]
                            : p.Wh1[gate][(size_t)(kk - 256) * HID_ + hid];
      w1[dst] = (kk < 256) ? f2bf(s1) : f2h(s1);   // H-part f16 (u8-decoded operand)
      w3[dst] = (kk < 256) ? f2bf(s3) : f2h(s3);
    }
    {  // mix weights: all f16 (both operand halves are u8-decoded)
      u16* w2 = (u16*)(smem + OFF_W2);
      int kk16 = tid >> 4, j2 = tid & 15;
      int hid2 = (c >> 1) * 16 + j2;
      for (int kk = kk16; kk < 1024; kk += 16) {
        int kb = kk >> 5, q2 = (kk >> 3) & 3, e = kk & 7;
        size_t dst = ((size_t)kb * 64 + q2 * 16 + j2) * 8 + e;
        float s = (kk < 512) ? p.Wxh[(size_t)kk * HID_ + hid2]
                             : p.Whh[(size_t)(kk - 512) * HID_ + hid2];
        w2[dst] = f2h(s);
      }
    }
    // B1 = bg - colsum(Wh)  (u8-bias fold for cell1's H input)
    {
      float* scr = (float*)(smem + OFF_DSM);
      int col32 = tid & 31, part = tid >> 5;
      int gt = col32 >> 3, jj = col32 & 7;
      int hid1 = c * 8 + jj;
      float s = 0.f;
      for (int k = part * 64; k < part * 64 + 64; k++)
        s += p.Wh[gt][(size_t)k * HID_ + hid1];
      scr[col32 * 8 + part] = s;
      __syncthreads();
      if (tid < 32) {
        float t2 = 0.f;
        for (int i2 = 0; i2 < 8; i2++) t2 += scr[tid * 8 + i2];
        ((float*)(smem + OFF_B1))[tid] = p.bg[tid >> 3][c * 8 + (tid & 7)] - t2;
      }
      __syncthreads();
    }
    // B2 = bh - colsum(Wxh) - colsum(Whh)
    {
      float* scr = (float*)(smem + OFF_DSM);
      int col = tid & 15, part = tid >> 4;
      int hid2 = (c >> 1) * 16 + col;
      float s = 0.f;
      for (int k = part * 32; k < part * 32 + 32; k++)
        s += p.Whh[(size_t)k * HID_ + hid2] + p.Wxh[(size_t)k * HID_ + hid2];
      scr[col * 16 + part] = s;
      __syncthreads();
      if (tid < 16) {
        float t2 = 0.f;
        for (int i2 = 0; i2 < 16; i2++) t2 += scr[tid * 16 + i2];
        ((float*)(smem + OFF_B2))[tid] = p.bh[(c >> 1) * 16 + tid] - t2;
      }
      __syncthreads();
    }
    if (tid < 32) {   // B3 plain (H1m unsigned u8 -> no fold)
      ((float*)(smem + OFF_B3))[tid] = p.bg1[tid >> 3][c * 8 + (tid & 7)];
    }
    float* Cs = (float*)(smem + OFF_C);
    float* C1s = (float*)(smem + OFF_C1);
    for (int it = 0; it < 2; it++) {
      int idx = tid + it * 256;
      int row = idx >> 3, j8 = idx & 7;
      float v = p.Cin[(size_t)(g * 64 + row) * HID_ + c * 8 + j8];
      Cs[row * 8 + j8] = v;
      C1s[row * 8 + j8] = v;
    }
  }
  // H(-1) and H1(-1) u8 init from Hin (biased encode, permuted; normal stores)
  for (int it = 0; it < 2; it++) {
    int idx = bi * 512 + tid + it * 256;
    float v = p.Hin[idx];
    float vc2 = fminf(fmaxf(v, -0.999f), 0.999f);
    u8 ev = (u8)((vc2 + 1.f) * 127.5f + 0.5f);
    int row = idx >> 9, k = idx & 511;
    Hq1[(size_t)row * 512 + permk(k)] = ev;
    H18[(size_t)row * 512 + permk(k)] = ev;
  }
  // Embedding gather
  for (int tt = 0; tt < 4; tt++) {
    int t0 = c * 4 + tt;
    for (int pp = 0; pp < 16; pp++) {
      int b = g * 64 + w * 16 + pp;
      int tok = p.X[(size_t)b * Tt + t0];
      const float4* er = (const float4*)(p.E + (size_t)tok * EMB_);
      float4 v = er[lane];
      u16x4 u; u.x = f2bf(v.x); u.y = f2bf(v.y); u.z = f2bf(v.z); u.w = f2bf(v.w);
      *(u16x4*)(Xe + ((size_t)t0 * Bb + b) * EMB_ + lane * 4) = u;
    }
  }
  groupbar_heavy(fl, c, 1);

  int cph = 0;

  // ---- P0: cell1(0): Hq1 -> Hq0 ----
  cell_phase_q(smem, OFF_W1, OFF_B1, OFF_C, Xe, Hq1, Hq0, g, c, w, lane);
  arrive_cnt(fl, c); ++cph;

  // ---- P1: mix(0) [w 0-1] + cell1(1) [w 2-3] ----
  wait_cnt(fl, cph);
  if (w < 2) {
    f32x4 macc = mix_part1_q(smem, Hq0, g, c, w, lane);
    mix_part2(smem, macc, H18, HM8, g, c, w, lane);
  } else {
    cell1_w23_q(smem, Xe + (size_t)1 * Bb * EMB_, Hq0, Hq1, g, c, lane, tid);
  }
  arrive_cnt(fl, c); ++cph;

  // ---- steady state ----
  for (int t = 0; t < Tt - 1; t++) {
    const u16* Xt = Xe + (size_t)t * Bb * EMB_;
    // ---------- Phase A_t: cell2(t) — u8 H1m panel, f16 MFMA, chunked ----------
    {
      const u16* wb3 = (const u16*)(smem + OFF_W3) + lane * 8;
      const u16* xrow = Xt + (size_t)(g * 64 + w * 16 + r) * EMB_;
      f32x4 acc0 = {0.f, 0.f, 0.f, 0.f}, acc1 = {0.f, 0.f, 0.f, 0.f};
      s16x8 xa[8];
#pragma unroll
      for (int kb = 0; kb < 8; kb++) xa[kb] = *(const s16x8*)(xrow + kb * 32 + q * 8);
#pragma unroll
      for (int kb = 0; kb < 8; kb++) {
        acc0 = mfma16(xa[kb], *(const s16x8*)(wb3 + (size_t)(kb * 2 + 0) * 512), acc0);
        acc1 = mfma16(xa[kb], *(const s16x8*)(wb3 + (size_t)(kb * 2 + 1) * 512), acc1);
      }
      wait_cnt(fl, cph);
      const u8* hrow8 = HM8 + (size_t)(g * 64 + w * 16 + r) * 512 + q * 16;
      u32x4 rw[8];
      ld_u8x8(rw, hrow8);
      __builtin_amdgcn_sched_barrier(0);
      f32x4 ah0 = {0.f, 0.f, 0.f, 0.f}, ah1 = {0.f, 0.f, 0.f, 0.f};
      WAITLDN(6);
#pragma unroll
      for (int jj = 0; jj < 2; jj++) {
        f16x8 f0 = dec8(rw[jj].x, rw[jj].y);
        f16x8 f1 = dec8(rw[jj].z, rw[jj].w);
        ah0 = mfma16h(f0, *(const f16x8*)(wb3 + (size_t)((2 * jj + 8) * 2 + 0) * 512), ah0);
        ah1 = mfma16h(f0, *(const f16x8*)(wb3 + (size_t)((2 * jj + 8) * 2 + 1) * 512), ah1);
        ah0 = mfma16h(f1, *(const f16x8*)(wb3 + (size_t)((2 * jj + 9) * 2 + 0) * 512), ah0);
        ah1 = mfma16h(f1, *(const f16x8*)(wb3 + (size_t)((2 * jj + 9) * 2 + 1) * 512), ah1);
      }
      WAITLDN(4);
#pragma unroll
      for (int jj = 2; jj < 4; jj++) {
        f16x8 f0 = dec8(rw[jj].x, rw[jj].y);
        f16x8 f1 = dec8(rw[jj].z, rw[jj].w);
        ah0 = mfma16h(f0, *(const f16x8*)(wb3 + (size_t)((2 * jj + 8) * 2 + 0) * 512), ah0);
        ah1 = mfma16h(f0, *(const f16x8*)(wb3 + (size_t)((2 * jj + 8) * 2 + 1) * 512), ah1);
        ah0 = mfma16h(f1, *(const f16x8*)(wb3 + (size_t)((2 * jj + 9) * 2 + 0) * 512), ah0);
        ah1 = mfma16h(f1, *(const f16x8*)(wb3 + (size_t)((2 * jj + 9) * 2 + 1) * 512), ah1);
      }
      WAITLDN(2);
#pragma unroll
      for (int jj = 4; jj < 6; jj++) {
        f16x8 f0 = dec8(rw[jj].x, rw[jj].y);
        f16x8 f1 = dec8(rw[jj].z, rw[jj].w);
        ah0 = mfma16h(f0, *(const f16x8*)(wb3 + (size_t)((2 * jj + 8) * 2 + 0) * 512), ah0);
        ah1 = mfma16h(f0, *(const f16x8*)(wb3 + (size_t)((2 * jj + 8) * 2 + 1) * 512), ah1);
        ah0 = mfma16h(f1, *(const f16x8*)(wb3 + (size_t)((2 * jj + 9) * 2 + 0) * 512), ah0);
        ah1 = mfma16h(f1, *(const f16x8*)(wb3 + (size_t)((2 * jj + 9) * 2 + 1) * 512), ah1);
      }
      WAITLDN(0);
#pragma unroll
      for (int jj = 6; jj < 8; jj++) {
        f16x8 f0 = dec8(rw[jj].x, rw[jj].y);
        f16x8 f1 = dec8(rw[jj].z, rw[jj].w);
        ah0 = mfma16h(f0, *(const f16x8*)(wb3 + (size_t)((2 * jj + 8) * 2 + 0) * 512), ah0);
        ah1 = mfma16h(f0, *(const f16x8*)(wb3 + (size_t)((2 * jj + 8) * 2 + 1) * 512), ah1);
        ah0 = mfma16h(f1, *(const f16x8*)(wb3 + (size_t)((2 * jj + 9) * 2 + 0) * 512), ah0);
        ah1 = mfma16h(f1, *(const f16x8*)(wb3 + (size_t)((2 * jj + 9) * 2 + 1) * 512), ah1);
      }
#pragma unroll
      for (int i = 0; i < 4; i++) {
        acc0[i] += ah0[i] * S_HM;
        acc1[i] += ah1[i] * S_HM;
      }
      cell2_epi(smem, OFF_B3, OFF_C1, acc0, acc1, H18, g, c, w, lane);
      arrive_cnt(fl, c); ++cph;
    }
    // ---------- Phase B_t: mix(t+1) [w 0-1] + cell1(t+2) [w 2-3, pre-wait] ----------
    {
      const u8* Hnew = (t & 1) ? Hq0 : Hq1;   // H(t+1)
      u8* Hdst1      = (t & 1) ? Hq1 : Hq0;   // H(t+2)
      f32x4 macc = {0.f, 0.f, 0.f, 0.f};
      if (w < 2) {
        macc = mix_part1_q(smem, Hnew, g, c, w, lane);
      } else if (t + 2 < Tt) {
        cell1_w23_q(smem, Xe + (size_t)(t + 2) * Bb * EMB_, Hnew, Hdst1, g, c, lane, tid);
      }
      wait_cnt(fl, cph);
      if (w < 2) mix_part2(smem, macc, H18, HM8, g, c, w, lane);
      arrive_cnt(fl, c); ++cph;
    }
  }

  // ---- epilogue: cell2(255) ----
  {
    const u16* Xt = Xe + (size_t)(Tt - 1) * Bb * EMB_;
    const u16* wb3 = (const u16*)(smem + OFF_W3) + lane * 8;
    const u16* xrow = Xt + (size_t)(g * 64 + w * 16 + r) * EMB_;
    f32x4 acc0 = {0.f, 0.f, 0.f, 0.f}, acc1 = {0.f, 0.f, 0.f, 0.f};
    s16x8 xa[8];
#pragma unroll
    for (int kb = 0; kb < 8; kb++) xa[kb] = *(const s16x8*)(xrow + kb * 32 + q * 8);
#pragma unroll
    for (int kb = 0; kb < 8; kb++) {
      acc0 = mfma16(xa[kb], *(const s16x8*)(wb3 + (size_t)(kb * 2 + 0) * 512), acc0);
      acc1 = mfma16(xa[kb], *(const s16x8*)(wb3 + (size_t)(kb * 2 + 1) * 512), acc1);
    }
    wait_cnt(fl, cph);
    const u8* hrow8 = HM8 + (size_t)(g * 64 + w * 16 + r) * 512 + q * 16;
    u32x4 rw[8];
    ld_u8x8(rw, hrow8);
    waitld();
    f32x4 ah0 = {0.f, 0.f, 0.f, 0.f}, ah1 = {0.f, 0.f, 0.f, 0.f};
#pragma unroll
    for (int jj = 0; jj < 8; jj++) {
      f16x8 f0 = dec8(rw[jj].x, rw[jj].y);
      f16x8 f1 = dec8(rw[jj].z, rw[jj].w);
      ah0 = mfma16h(f0, *(const f16x8*)(wb3 + (size_t)((2 * jj + 8) * 2 + 0) * 512), ah0);
      ah1 = mfma16h(f0, *(const f16x8*)(wb3 + (size_t)((2 * jj + 8) * 2 + 1) * 512), ah1);
      ah0 = mfma16h(f1, *(const f16x8*)(wb3 + (size_t)((2 * jj + 9) * 2 + 0) * 512), ah0);
      ah1 = mfma16h(f1, *(const f16x8*)(wb3 + (size_t)((2 * jj + 9) * 2 + 1) * 512), ah1);
    }
#pragma unroll
    for (int i = 0; i < 4; i++) {
      acc0[i] += ah0[i] * S_HM;
      acc1[i] += ah1[i] * S_HM;
    }
    cell2_epi(smem, OFF_B3, OFF_C1, acc0, acc1, H18, g, c, w, lane);
  }

  // ---- final GEMM: u8 H1 (cached loads post-donebar), f16 Wf, bias-corrected ----
  donebar(dn, bi);
  if (bi < 250) {
    const int n0 = bi * 128;
    _Float16* Wf = (_Float16*)smem;   // [16 kb][8 nt][64 lane][8] f16
    for (int idx = tid; idx < 512 * 128; idx += NTHR) {
      int k = idx >> 7, nn2 = idx & 127;
      int nt = nn2 >> 4, rr = nn2 & 15;
      int kb = k >> 5, q2 = (k >> 3) & 3, e = k & 7;
      Wf[((size_t)(kb * 8 + nt) * 64 + q2 * 16 + rr) * 8 + e] =
          (_Float16)p.Whq[(size_t)k * NCLS + n0 + nn2];
    }
    float* bqs = (float*)(smem + OFF_C);
    __syncthreads();
    if (tid < 128) {       // bqs = bq - colsum(Whq)  (u8 bias-fold), from LDS
      int nt = tid >> 4, rr = tid & 15;
      float s = 0.f;
      for (int kb = 0; kb < 16; kb++)
        for (int q2 = 0; q2 < 4; q2++)
#pragma unroll
          for (int e = 0; e < 8; e++)
            s += (float)Wf[((size_t)(kb * 8 + nt) * 64 + q2 * 16 + rr) * 8 + e];
      bqs[tid] = p.bq[n0 + tid] - s;
    }
    __syncthreads();
    const int r2 = lane & 15, q2 = lane >> 4;
    for (int mt = 0; mt < 4; mt++) {
      int rowb = mt * 64 + w * 16;
      const u8* h1base = H18 + (size_t)(rowb + r2) * 512 + q2 * 16;
      f16x8 haf[16];
#pragma unroll
      for (int jj = 0; jj < 8; jj++) {
        u32x4 rwv = *(const u32x4*)(h1base + jj * 64);
        haf[2 * jj]     = dec8(rwv.x, rwv.y);
        haf[2 * jj + 1] = dec8(rwv.z, rwv.w);
      }
      f32x4 acc[8];
#pragma unroll
      for (int nt = 0; nt < 8; nt++) acc[nt] = (f32x4){0.f, 0.f, 0.f, 0.f};
      for (int kb = 0; kb < 16; kb++) {
#pragma unroll
        for (int nt = 0; nt < 8; nt++) {
          f16x8 b = *(const f16x8*)(Wf + ((size_t)(kb * 8 + nt) * 64 + lane) * 8);
          acc[nt] = mfma16h(haf[kb], b, acc[nt]);
        }
      }
#pragma unroll
      for (int nt = 0; nt < 8; nt++)
#pragma unroll
        for (int i = 0; i < 4; i++)
          p.out[(size_t)(rowb + q2 * 4 + i) * NCLS + n0 + nt * 16 + r2] =
              acc[nt][i] * S_H1 + bqs[nt * 16 + r2];
    }
  }
}

extern "C" void kernel_launch(void* const* d_in, const int* in_sizes, int n_in,
                              void* d_out, int out_size, void* d_ws, size_t ws_size,
                              hipStream_t stream) {
  (void)in_sizes; (void)n_in; (void)out_size; (void)ws_size;
  Params p;
  p.X   = (const int*)d_in[0];
  p.Hin = (const float*)d_in[1];
  p.Cin = (const float*)d_in[2];
  p.E   = (const float*)d_in[3];
  for (int gidx = 0; gidx < 4; gidx++) {
    int base = 4 + gidx * 6;
    p.Wx[gidx]  = (const float*)d_in[base + 0];
    p.Wh[gidx]  = (const float*)d_in[base + 1];
    p.bg[gidx]  = (const float*)d_in[base + 2];
    p.Wx1[gidx] = (const float*)d_in[base + 3];
    p.Wh1[gidx] = (const float*)d_in[base + 4];
    p.bg1[gidx] = (const float*)d_in[base + 5];
  }
  p.Wxh = (const float*)d_in[28];
  p.Whh = (const float*)d_in[29];
  p.bh  = (const float*)d_in[30];
  p.Whq = (const float*)d_in[31];
  p.bq  = (const float*)d_in[32];
  p.out = (float*)d_out;
  p.ws  = (char*)d_ws;

  hipFuncSetAttribute(reinterpret_cast<const void*>(lstm_pers),
                      hipFuncAttributeMaxDynamicSharedMemorySize, SMEM_BYTES);
  lstm_pers<<<dim3(NWG), dim3(NTHR), SMEM_BYTES, stream>>>(p);
}